// Round 1
// baseline (170.766 us; speedup 1.0000x reference)
//
#include <hip/hip_runtime.h>
#include <math.h>

// SIREN forward: coords [N,3] -> first(3->5,sin) -> 256 x hidden(5->5,sin) -> final(5->1)
// Output layout: d_out[0..N) = net output, d_out[N..4N) = coords passthrough.
//
// Design notes (round 1):
//  - One thread per point; 5 activations live in VGPRs.
//  - Weights are indexed only by the (uniform) layer counter -> compiler emits
//    scalar loads (s_load), which cost no VALU issue slots and hit the K$/L2
//    (weights total ~31 KB, fully cached).
//  - sin(30*z) = v_sin_f32(fract(z * 30/(2*pi))): 1 mul + 1 fract + 1 sin per
//    neuron instead of libm sinf's ~25-instr reduction path. HW sin abs error
//    ~1e-6, same order as f32 matvec rounding; threshold is 2e-2.

#define SIREN_HID 5
#define SIREN_NLAYERS 256

// 30 / (2*pi)
#define SIREN_REV 4.774648292756860f

__device__ __forceinline__ float siren_sin30(float z) {
    float t = z * SIREN_REV;
    return __builtin_amdgcn_sinf(__builtin_amdgcn_fractf(t));
}

__global__ __launch_bounds__(256)
void siren_fwd(const float* __restrict__ coords,
               const float* __restrict__ Wf,   // [5][3]
               const float* __restrict__ bf,   // [5]
               const float* __restrict__ Wh,   // [256][5][5]
               const float* __restrict__ bh,   // [256][5]
               const float* __restrict__ Wfin, // [1][5]
               const float* __restrict__ bfin, // [1]
               float* __restrict__ out, int N)
{
    int i = blockIdx.x * blockDim.x + threadIdx.x;
    if (i >= N) return;

    float c0 = coords[3 * i + 0];
    float c1 = coords[3 * i + 1];
    float c2 = coords[3 * i + 2];

    // first layer: h_j = sin(30 * (c . Wf[j,:] + bf[j]))
    float h0, h1, h2, h3, h4;
    {
        float t0 = fmaf(c2, Wf[0 * 3 + 2], fmaf(c1, Wf[0 * 3 + 1], fmaf(c0, Wf[0 * 3 + 0], bf[0])));
        float t1 = fmaf(c2, Wf[1 * 3 + 2], fmaf(c1, Wf[1 * 3 + 1], fmaf(c0, Wf[1 * 3 + 0], bf[1])));
        float t2 = fmaf(c2, Wf[2 * 3 + 2], fmaf(c1, Wf[2 * 3 + 1], fmaf(c0, Wf[2 * 3 + 0], bf[2])));
        float t3 = fmaf(c2, Wf[3 * 3 + 2], fmaf(c1, Wf[3 * 3 + 1], fmaf(c0, Wf[3 * 3 + 0], bf[3])));
        float t4 = fmaf(c2, Wf[4 * 3 + 2], fmaf(c1, Wf[4 * 3 + 1], fmaf(c0, Wf[4 * 3 + 0], bf[4])));
        h0 = siren_sin30(t0);
        h1 = siren_sin30(t1);
        h2 = siren_sin30(t2);
        h3 = siren_sin30(t3);
        h4 = siren_sin30(t4);
    }

    // 256 hidden layers: h'_j = sin(30 * (h . w[j,:] + b[j]))
#pragma unroll 4
    for (int l = 0; l < SIREN_NLAYERS; ++l) {
        const float* w = Wh + l * (SIREN_HID * SIREN_HID);
        const float* b = bh + l * SIREN_HID;
        float t0 = fmaf(h4, w[ 4], fmaf(h3, w[ 3], fmaf(h2, w[ 2], fmaf(h1, w[ 1], fmaf(h0, w[ 0], b[0])))));
        float t1 = fmaf(h4, w[ 9], fmaf(h3, w[ 8], fmaf(h2, w[ 7], fmaf(h1, w[ 6], fmaf(h0, w[ 5], b[1])))));
        float t2 = fmaf(h4, w[14], fmaf(h3, w[13], fmaf(h2, w[12], fmaf(h1, w[11], fmaf(h0, w[10], b[2])))));
        float t3 = fmaf(h4, w[19], fmaf(h3, w[18], fmaf(h2, w[17], fmaf(h1, w[16], fmaf(h0, w[15], b[3])))));
        float t4 = fmaf(h4, w[24], fmaf(h3, w[23], fmaf(h2, w[22], fmaf(h1, w[21], fmaf(h0, w[20], b[4])))));
        h0 = siren_sin30(t0);
        h1 = siren_sin30(t1);
        h2 = siren_sin30(t2);
        h3 = siren_sin30(t3);
        h4 = siren_sin30(t4);
    }

    // final linear (no sine)
    float o = fmaf(h4, Wfin[4], fmaf(h3, Wfin[3], fmaf(h2, Wfin[2], fmaf(h1, Wfin[1], fmaf(h0, Wfin[0], bfin[0])))));
    out[i] = o;

    // coords passthrough (second tuple element)
    float* oc = out + N;
    oc[3 * i + 0] = c0;
    oc[3 * i + 1] = c1;
    oc[3 * i + 2] = c2;
}

extern "C" void kernel_launch(void* const* d_in, const int* in_sizes, int n_in,
                              void* d_out, int out_size, void* d_ws, size_t ws_size,
                              hipStream_t stream) {
    const float* coords = (const float*)d_in[0];
    const float* Wf     = (const float*)d_in[1];
    const float* bf     = (const float*)d_in[2];
    const float* Wh     = (const float*)d_in[3];
    const float* bh     = (const float*)d_in[4];
    const float* Wfin   = (const float*)d_in[5];
    const float* bfin   = (const float*)d_in[6];

    int N = in_sizes[0] / 3;
    float* out = (float*)d_out;

    dim3 block(256);
    dim3 grid((N + 255) / 256);
    hipLaunchKernelGGL(siren_fwd, grid, block, 0, stream,
                       coords, Wf, bf, Wh, bh, Wfin, bfin, out, N);
}